// Round 11
// baseline (178.737 us; speedup 1.0000x reference)
//
#include <hip/hip_runtime.h>
#include <math.h>

#define N 512
#define BATCH 128
#define EPS 1e-8f
#define TPB 1024         // 16 waves
#define NW 16
#define KP 304           // max kp for direct LDS path
#define LN2 0.69314718055994530942f
#define SPLIT 144        // zcase/overflow split point (multiple of 16)
#define GSTR 152         // G LDS row stride in halves (mult of 8 -> 16B rows)
#define SLD2 372         // S slab row stride (floats)

typedef _Float16 f16;
typedef _Float16 f16x8 __attribute__((ext_vector_type(8)));
typedef float f32x4 __attribute__((ext_vector_type(4)));

// packed fp16 triangle: row r starts 16B-aligned, length rup(r+1,8)
__device__ __forceinline__ int lh_base(int r) {
    const int a = r >> 3, b = r & 7;
    return 8 * (a + 1) * (4 * a + b);
}

// LDS arena layouts (bytes):
// MODE0 (batch):  Lh(304) 0..94848 | P f16 [512][24] @94848 | M @119424 (end 120704)
// MODE1 (stage1): Lh(144) 0..21888 | G f16 [368][GSTR] @22016..133888 |
//                 P @133888 | M @158464 (end 159744)
// MODE2 (stage2): Lh(368) 0..138368 | P @138368 | M @156032 (end 157312)
#define G1_OFF 22016
#define ARENA_SZ 159744
#define SLAB_BYTES (368 * SLD2 * 4)   // S handoff slab (global), 547584

__device__ __forceinline__ float rdl(float v, int l) {
    return __builtin_bit_cast(float,
        __builtin_amdgcn_readlane(__builtin_bit_cast(int, v), l));
}

__device__ __forceinline__ void tri_map(int e, int* r_out, int* c_out) {
    int rr = (int)((sqrtf(8.0f * (float)e + 1.0f) - 1.0f) * 0.5f);
    while ((((rr + 1) * (rr + 2)) >> 1) <= e) ++rr;
    while (((rr * (rr + 1)) >> 1) > e) --rr;
    *r_out = rr;
    *c_out = e - ((rr * (rr + 1)) >> 1);
}

// ---------- L = B^T B + EPS*I : 64x64 register-tiled ----------
__global__ __launch_bounds__(256) void compute_L(const float* __restrict__ B,
                                                 float* __restrict__ L) {
    const int r0 = blockIdx.x * 64, c0 = blockIdx.y * 64;
    const int tx = threadIdx.x & 15, ty = threadIdx.x >> 4;
    __shared__ float Bi[16][64];
    __shared__ float Bj[16][64];
    float acc[4][4] = {};
    for (int k0 = 0; k0 < N; k0 += 16) {
#pragma unroll
        for (int q = 0; q < 4; ++q) {
            const int e = threadIdx.x + q * 256;
            const int kr = e >> 6, cc = e & 63;
            Bi[kr][cc] = B[(k0 + kr) * N + r0 + cc];
            Bj[kr][cc] = B[(k0 + kr) * N + c0 + cc];
        }
        __syncthreads();
#pragma unroll
        for (int kq = 0; kq < 16; ++kq) {
            float a[4], b[4];
#pragma unroll
            for (int q = 0; q < 4; ++q) {
                a[q] = Bi[kq][ty * 4 + q];
                b[q] = Bj[kq][tx * 4 + q];
            }
#pragma unroll
            for (int i = 0; i < 4; ++i)
#pragma unroll
                for (int j = 0; j < 4; ++j) acc[i][j] = fmaf(a[i], b[j], acc[i][j]);
        }
        __syncthreads();
    }
#pragma unroll
    for (int i = 0; i < 4; ++i) {
        const int r = r0 + ty * 4 + i;
        f32x4 v;
#pragma unroll
        for (int j = 0; j < 4; ++j) {
            const int c = c0 + tx * 4 + j;
            v[j] = acc[i][j] + ((r == c) ? EPS : 0.0f);
        }
        *(f32x4*)(&L[r * N + c0 + tx * 4]) = v;
    }
}

// gather one source entry. MODE 0/1: from L via idx (+add1 diag); MODE 2: from S (lower tri)
template <int MODE>
__device__ __forceinline__ float gath(const float* __restrict__ L,
                                      const float* __restrict__ S, const short* idx,
                                      int k, bool add1, int gr, int gc) {
    if constexpr (MODE <= 1) {
        if (gr < k && gc < k) {
            float v = L[(int)idx[gr] * N + (int)idx[gc]];
            if (add1 && gr == gc) v += 1.0f;
            return v;
        }
        return (gr == gc) ? 1.0f : 0.0f;
    } else {
        if (gr < k && gc < k) {
            const int r2 = gr > gc ? gr : gc, c2 = gr > gc ? gc : gr;
            return S[r2 * SLD2 + c2];
        }
        return (gr == gc) ? 1.0f : 0.0f;
    }
}

// ---------- left-looking PW=16 panel Cholesky ----------
// MODE 0: all rows in LDS Lh.  MODE 1: rows >= SPLIT go to LDS G buffer.
// MODE 2: source = S slab (global). Returns sum(log2(pivots)) on wave 0.
template <int MODE, int CT>
__device__ float chol_panels(char* arena, const float* __restrict__ S,
                             const float* __restrict__ L, const short* idx,
                             int k, int rows, int ncols, bool add1) {
    const int tid = threadIdx.x;
    const int lane = tid & 63, wv = tid >> 6;
    constexpr int p_off = (MODE == 0) ? 94848 : (MODE == 1) ? 133888 : 138368;
    constexpr int m_off = (MODE == 0) ? 119424 : (MODE == 1) ? 158464 : 156032;
    f16* Lh = (f16*)arena;
    f16* Gl = (f16*)(arena + G1_OFF);
    f16* P = (f16*)(arena + p_off);       // [rows_rel][24] fp16 staging
    f16* M = (f16*)(arena + m_off);       // [16][40] fp16
    const int frow = lane & 15, koff = (lane >> 4) * 8;
    const int crow = (lane >> 4) * 4, ccol = lane & 15;

    float lg2 = 0.0f;
    const int npan = ncols >> 4;
    for (int p = 0; p < npan; ++p) {
        const int jb = p << 4;
        const int ntile = (rows - jb) >> 4;

        // tile ownership: wave 0 -> diag only; wave w>=1 -> tiles w, w+15, ...
        int r0_[CT], baseA_[CT];
        bool val_[CT], isg_[CT];
#pragma unroll
        for (int it = 0; it < CT; ++it) {
            const int ti = (wv == 0) ? (it == 0 ? 0 : (1 << 20)) : (wv + 15 * it);
            const bool v = ti < ntile;
            const int r0 = jb + ((v ? ti : 0) << 4);
            r0_[it] = r0;
            val_[it] = v;
            const bool gg = (MODE == 1) && v && (r0 >= SPLIT);
            isg_[it] = gg;
            baseA_[it] = gg ? ((r0 - SPLIT + frow) * GSTR + koff)
                            : (lh_base(r0 + frow) + koff);
        }
        const int baseB = lh_base(jb + frow) + koff;

        // scattered gathers (issued early, consumed at P store)
        f32x4 g_[CT];
#pragma unroll
        for (int it = 0; it < CT; ++it)
            if (val_[it]) {
#pragma unroll
                for (int q = 0; q < 4; ++q)
                    g_[it][q] = gath<MODE>(L, S, idx, k, add1, r0_[it] + crow + q, jb + ccol);
            }

        // ---- (a) kk-chain, strip-mined 4 chunks per group
        const int nkk = (jb + 31) >> 5;
        f32x4 acc_[CT];
#pragma unroll
        for (int it = 0; it < CT; ++it) acc_[it] = (f32x4){0.f, 0.f, 0.f, 0.f};

        for (int cg = 0; cg < nkk; cg += 4) {
            f16x8 A_[4][CT], B_[4];
#pragma unroll
            for (int u = 0; u < 4; ++u) {
                const int c = cg + u;
                const int kk = c << 5;
                const bool ok = (c < nkk) && (kk + koff < jb);
                B_[u] = ok ? *(const f16x8*)(&Lh[baseB + kk]) : (f16x8){};
#pragma unroll
                for (int it = 0; it < CT; ++it) {
                    f16x8 vv = {};
                    if (ok && val_[it]) {
                        if (MODE == 1 && isg_[it]) vv = *(const f16x8*)(&Gl[baseA_[it] + kk]);
                        else vv = *(const f16x8*)(&Lh[baseA_[it] + kk]);
                    }
                    A_[u][it] = vv;
                }
            }
#pragma unroll
            for (int u = 0; u < 4; ++u) {
                if (cg + u < nkk) {
#pragma unroll
                    for (int it = 0; it < CT; ++it)
                        if (val_[it])
                            acc_[it] = __builtin_amdgcn_mfma_f32_16x16x32_f16(
                                A_[u][it], B_[u], acc_[it], 0, 0, 0);
                }
            }
        }

        // P store (own rows, fp16) — LDS in-order per wave, same-wave re-read safe
#pragma unroll
        for (int it = 0; it < CT; ++it)
            if (val_[it]) {
                const int lr = r0_[it] - jb;
#pragma unroll
                for (int q = 0; q < 4; ++q)
                    P[(lr + crow + q) * 24 + ccol] = (f16)(g_[it][q] - acc_[it][q]);
            }

        // own (c) A-frags straight from own P rows (fp16, no convert)
        f16x8 afs[CT];
#pragma unroll
        for (int it = 0; it < CT; ++it) {
            f16x8 af = {};
            if (val_[it] && wv != 0 && koff < 16) {
                const int lr = r0_[it] - jb;
                af = *(const f16x8*)(&P[(lr + frow) * 24 + koff]);
            }
            afs[it] = af;
        }

        // ---- (b) wave 0: factor diag via column ops; inverse as by-product
        if (wv == 0) {
            const int r = lane & 15;
            float row[16], w[16];
#pragma unroll
            for (int c = 0; c < 16; ++c) row[c] = (float)P[r * 24 + c];
#pragma unroll
            for (int c = 0; c < 16; ++c) w[c] = (c == r) ? 1.0f : 0.0f;
#pragma unroll
            for (int j = 0; j < 16; ++j) {
                const float piv = rdl(row[j], j);
                lg2 += __log2f(piv);
                const float irs = rsqrtf(piv);
                row[j] *= irs;
                w[j] *= irs;
#pragma unroll
                for (int cc = j + 1; cc < 16; ++cc) {
                    const float s = rdl(row[j], cc);   // L[cc][j], uniform
                    row[cc] = fmaf(-row[j], s, row[cc]);
                    w[cc] = fmaf(-s, w[j], w[cc]);
                }
            }
            if (lane < 16) {
                f16x8 hv0, hv1;
#pragma unroll
                for (int m = 0; m < 8; ++m) {
                    hv0[m] = (f16)row[m];
                    hv1[m] = (f16)row[8 + m];
                }
                *(f16x8*)(&Lh[lh_base(jb + lane) + jb]) = hv0;
                if (lane >= 8) *(f16x8*)(&Lh[lh_base(jb + lane) + jb + 8]) = hv1;
            }
            if (lane < 32) {
#pragma unroll
                for (int i = 0; i < 16; ++i)
                    M[i * 40 + lane] = (lane < 16) ? (f16)w[i] : (f16)0.0f;
            }
        }
        __syncthreads();            // barrier 1: M + diag factor rows visible

        // ---- (c) X = S_tile · M^T : one MFMA per owned tile
        const f16x8 bfM = *(const f16x8*)(&M[frow * 40 + koff]);
#pragma unroll
        for (int it = 0; it < CT; ++it) {
            if (val_[it] && wv != 0) {
                f32x4 xx = {0.f, 0.f, 0.f, 0.f};
                xx = __builtin_amdgcn_mfma_f32_16x16x32_f16(afs[it], bfM, xx, 0, 0, 0);
#pragma unroll
                for (int q = 0; q < 4; ++q) {
                    const int gr = r0_[it] + crow + q;
                    const f16 h = (f16)xx[q];
                    if (MODE == 1 && gr >= SPLIT) Gl[(gr - SPLIT) * GSTR + jb + ccol] = h;
                    else Lh[lh_base(gr) + jb + ccol] = h;
                }
            }
        }
        __syncthreads();            // barrier 2: factor cols jb..jb+15 published
    }
    return lg2;
}

// ---------- S = A22 - G·G^T, G in LDS; S (fp32) streamed to global ----------
__device__ void schur_gemm(char* arena, float* __restrict__ S,
                           const float* __restrict__ L, const short* idx,
                           int k, int k2p, bool add1) {
    const int tid = threadIdx.x;
    const int lane = tid & 63, wv = tid >> 6;
    const f16* Gl = (const f16*)(arena + G1_OFF);
    const int frow = lane & 15, koff = (lane >> 4) * 8;
    const int crow = (lane >> 4) * 4, ccol = lane & 15;
    const int nt2 = k2p >> 4, TT = (nt2 * (nt2 + 1)) >> 1;
    const int nkk = (SPLIT + 31) >> 5;   // 5
    for (int e = wv; e < TT; e += NW) {
        int R, C;
        tri_map(e, &R, &C);
        const int r0 = R << 4, c0 = C << 4;
        f32x4 g;
#pragma unroll
        for (int q = 0; q < 4; ++q) {
            const int gr = SPLIT + r0 + crow + q, gc = SPLIT + c0 + ccol;
            float v;
            if (gr < k && gc < k) {
                v = L[(int)idx[gr] * N + (int)idx[gc]];
                if (add1 && gr == gc) v += 1.0f;
            } else v = (gr == gc) ? 1.0f : 0.0f;
            g[q] = v;
        }
        const int ba = (r0 + frow) * GSTR + koff, bb = (c0 + frow) * GSTR + koff;
        f32x4 acc = {0.f, 0.f, 0.f, 0.f};
        for (int cg = 0; cg < nkk; cg += 4) {
            f16x8 A_[4], B_[4];
#pragma unroll
            for (int u = 0; u < 4; ++u) {
                const int c = cg + u, kk = c << 5;
                const bool ok = (c < nkk) && (kk + koff < SPLIT);
                A_[u] = ok ? *(const f16x8*)(&Gl[ba + kk]) : (f16x8){};
                B_[u] = ok ? *(const f16x8*)(&Gl[bb + kk]) : (f16x8){};
            }
#pragma unroll
            for (int u = 0; u < 4; ++u)
                if (cg + u < nkk)
                    acc = __builtin_amdgcn_mfma_f32_16x16x32_f16(A_[u], B_[u], acc, 0, 0, 0);
        }
#pragma unroll
        for (int q = 0; q < 4; ++q)
            S[(r0 + crow + q) * SLD2 + c0 + ccol] = g[q] - acc[q];
    }
}

// ---------- one block per batch item; block BATCH = logdet(L+I) ----------
// __launch_bounds__(TPB, 4): 4 waves/SIMD = exactly this block's 16 waves.
// LDS (157 KB) caps us at 1 block/CU regardless, so let the allocator use the
// full 128 VGPRs instead of the 64 it picked for an unreachable 2-block/CU.
__global__ __launch_bounds__(TPB, 4) void chol_all(const int* __restrict__ x,
                                                   const float* __restrict__ L,
                                                   char* __restrict__ slabs, int nslabs,
                                                   float* __restrict__ logs) {
    const int b = blockIdx.x;
    const int tid = threadIdx.x;
    const int lane = tid & 63, wv = tid >> 6;
    __shared__ __align__(16) char arena[ARENA_SZ];
    __shared__ short idx[N];
    __shared__ int wcnt[NW];

    const bool zc = (b == BATCH);
    const bool inx = tid < N;
    const bool act = zc ? inx : (inx && x[(size_t)b * N + tid] != 0);
    const unsigned long long m = __ballot(act);
    if (lane == 0) wcnt[wv] = __popcll(m);
    __syncthreads();
    int off = 0, ktot = 0;
    for (int q = 0; q < NW; ++q) {
        if (q < wv) off += wcnt[q];
        ktot += wcnt[q];
    }
    if (act) idx[off + __popcll(m & ((1ULL << lane) - 1ULL))] = (short)tid;
    __syncthreads();

    const int k = ktot;
    const int kp = (k + 15) & ~15;

    float lg2;
    if (!zc && kp <= KP) {
        lg2 = chol_panels<0, 2>(arena, nullptr, L, idx, k, kp, kp, false);
    } else {
        const int si = zc ? 0 : (nslabs > 1 ? 1 + (b % (nslabs - 1)) : 0);
        float* S = (float*)(slabs + (size_t)si * SLAB_BYTES);
        const int k2 = k - SPLIT, k2p = kp - SPLIT;
        lg2 = chol_panels<1, 3>(arena, nullptr, L, idx, k, kp, SPLIT, zc);
        schur_gemm(arena, S, L, idx, k, k2p, zc);
        __syncthreads();   // all G reads done before stage2 overwrites the arena
        lg2 += chol_panels<2, 2>(arena, S, L, idx, k2, k2p, k2p, false);
    }
    if (tid == 0) logs[b] = lg2 * LN2;
}

__global__ void finalize(const float* __restrict__ logs, float* __restrict__ out) {
    const int i = threadIdx.x;
    out[i] = logs[i] - logs[BATCH];
}

extern "C" void kernel_launch(void* const* d_in, const int* in_sizes, int n_in,
                              void* d_out, int out_size, void* d_ws, size_t ws_size,
                              hipStream_t stream) {
    const int* x = (const int*)d_in[0];
    const float* B = (const float*)d_in[1];
    float* out = (float*)d_out;

    char* ws = (char*)d_ws;
    const size_t L_bytes = (size_t)N * N * 4;  // 1 MB
    float* L = (float*)ws;
    float* logs = (float*)(ws + L_bytes);
    const size_t head = L_bytes + 4096;
    char* slabs = ws + head;
    int nslabs = (ws_size > head) ? (int)((ws_size - head) / SLAB_BYTES) : 1;
    if (nslabs < 1) nslabs = 1;
    if (nslabs > 9) nslabs = 9;

    compute_L<<<dim3(8, 8), 256, 0, stream>>>(B, L);
    chol_all<<<BATCH + 1, TPB, 0, stream>>>(x, L, slabs, nslabs, logs);
    finalize<<<1, BATCH, 0, stream>>>(logs, out);
}

// Round 12
// 158.986 us; speedup vs baseline: 1.1242x; 1.1242x over previous
//
#include <hip/hip_runtime.h>
#include <math.h>

#define N 512
#define BATCH 128
#define EPS 1e-8f
#define TPB 1024         // 16 waves
#define NW 16
#define KP 304           // max kp for direct LDS path
#define LN2 0.69314718055994530942f
#define SPLIT 160        // zcase split (multiple of 32)
#define GSTR 160         // G LDS row stride in halves
#define SLD2 356         // S slab row stride (floats)
#define SLAB_BYTES (352 * SLD2 * 4)

typedef _Float16 f16;
typedef _Float16 f16x8 __attribute__((ext_vector_type(8)));
typedef float f32x4 __attribute__((ext_vector_type(4)));

// packed fp16 triangle: row r starts 16B-aligned, length rup(r+1,8)
__device__ __forceinline__ int lh_base(int r) {
    const int a = r >> 3, b = r & 7;
    return 8 * (a + 1) * (4 * a + b);
}

// arena layout (bytes):
// MODE0: Lh tri(304)=94848 | scr 16x1152 @94848 | M @113280 (end 115840)
// MODE1: Lh tri(160)=26880 | G [352][GSTR] @26880..139520 | scr @139520 | M @157952 (end 160512)
// MODE2: Lh tri(352)=126720 | scr @126720 | M @145152 (end 147712)
#define G1_OFF   26880
#define SCR0_OFF 94848
#define M0_OFF   113280
#define SCR1_OFF 139520
#define M1_OFF   157952
#define SCR2_OFF 126720
#define M2_OFF   145152
#define ARENA_SZ 160512

__device__ __forceinline__ float rdl(float v, int l) {
    return __builtin_bit_cast(float,
        __builtin_amdgcn_readlane(__builtin_bit_cast(int, v), l));
}

__device__ __forceinline__ void tri_map(int e, int* r_out, int* c_out) {
    int rr = (int)((sqrtf(8.0f * (float)e + 1.0f) - 1.0f) * 0.5f);
    while ((((rr + 1) * (rr + 2)) >> 1) <= e) ++rr;
    while (((rr * (rr + 1)) >> 1) > e) --rr;
    *r_out = rr;
    *c_out = e - ((rr * (rr + 1)) >> 1);
}

// ---------- L = B^T B + EPS*I : 64x64 register-tiled ----------
__global__ __launch_bounds__(256) void compute_L(const float* __restrict__ B,
                                                 float* __restrict__ L) {
    const int r0 = blockIdx.x * 64, c0 = blockIdx.y * 64;
    const int tx = threadIdx.x & 15, ty = threadIdx.x >> 4;
    __shared__ float Bi[16][64];
    __shared__ float Bj[16][64];
    float acc[4][4] = {};
    for (int k0 = 0; k0 < N; k0 += 16) {
#pragma unroll
        for (int q = 0; q < 4; ++q) {
            const int e = threadIdx.x + q * 256;
            const int kr = e >> 6, cc = e & 63;
            Bi[kr][cc] = B[(k0 + kr) * N + r0 + cc];
            Bj[kr][cc] = B[(k0 + kr) * N + c0 + cc];
        }
        __syncthreads();
#pragma unroll
        for (int kq = 0; kq < 16; ++kq) {
            float a[4], b[4];
#pragma unroll
            for (int q = 0; q < 4; ++q) {
                a[q] = Bi[kq][ty * 4 + q];
                b[q] = Bj[kq][tx * 4 + q];
            }
#pragma unroll
            for (int i = 0; i < 4; ++i)
#pragma unroll
                for (int j = 0; j < 4; ++j) acc[i][j] = fmaf(a[i], b[j], acc[i][j]);
        }
        __syncthreads();
    }
#pragma unroll
    for (int i = 0; i < 4; ++i) {
        const int r = r0 + ty * 4 + i;
        f32x4 v;
#pragma unroll
        for (int j = 0; j < 4; ++j) {
            const int c = c0 + tx * 4 + j;
            v[j] = acc[i][j] + ((r == c) ? EPS : 0.0f);
        }
        *(f32x4*)(&L[r * N + c0 + tx * 4]) = v;
    }
}

// gather: MODE 0/1 from L via idx (+add1 diag); MODE 2 from S slab (lower tri)
template <int MODE>
__device__ __forceinline__ float gath(const float* __restrict__ L,
                                      const float* __restrict__ S, const short* idx,
                                      int k, bool add1, int gr, int gc) {
    if constexpr (MODE <= 1) {
        if (gr < k && gc < k) {
            float v = L[(int)idx[gr] * N + (int)idx[gc]];
            if (add1 && gr == gc) v += 1.0f;
            return v;
        }
        return (gr == gc) ? 1.0f : 0.0f;
    } else {
        if (gr < k && gc < k) {
            const int r2 = gr > gc ? gr : gc, c2 = gr > gc ? gc : gr;
            return S[r2 * SLD2 + c2];
        }
        return (gr == gc) ? 1.0f : 0.0f;
    }
}

// ---------- 32-col-panel left-looking Cholesky, one barrier pair per panel ----
template <int MODE>
__device__ float chol32(char* arena, const float* __restrict__ S,
                        const float* __restrict__ L, const short* idx,
                        int k, int rows, int ncols, bool add1) {
    const int tid = threadIdx.x;
    const int lane = tid & 63, wv = tid >> 6;
    constexpr int scr_off = (MODE == 0) ? SCR0_OFF : (MODE == 1) ? SCR1_OFF : SCR2_OFF;
    constexpr int m_off = (MODE == 0) ? M0_OFF : (MODE == 1) ? M1_OFF : M2_OFF;
    f16* Lh = (f16*)arena;
    f16* Gl = (f16*)(arena + G1_OFF);
    f16* scr = (f16*)(arena + scr_off) + wv * 576;   // per-wave [16][36]
    f16* Mm = (f16*)(arena + m_off);                 // M0 [16][40], M1 at +640
    const int frow = lane & 15, koff = (lane >> 4) * 8;
    const int crow = (lane >> 4) * 4, ccol = lane & 15;
    const f32x4 zz = {0.f, 0.f, 0.f, 0.f};

    float lg2 = 0.0f;

    auto ld_af = [&]() -> f16x8 {                    // zero k-elems 16..31
        if (koff < 16) return *(const f16x8*)(&scr[frow * 36 + koff]);
        f16x8 z = {};
        return z;
    };
    auto scr_st = [&](const f32x4& v) {
#pragma unroll
        for (int q = 0; q < 4; ++q) scr[(crow + q) * 36 + ccol] = (f16)v[q];
    };
    auto factor16 = [&](int rbase, int cbase, f16* mdst) {
        float row[16], w[16];
#pragma unroll
        for (int c = 0; c < 16; ++c) row[c] = (float)scr[frow * 36 + c];
#pragma unroll
        for (int c = 0; c < 16; ++c) w[c] = (c == frow) ? 1.0f : 0.0f;
#pragma unroll
        for (int j = 0; j < 16; ++j) {
            const float piv = rdl(row[j], j);
            lg2 += __log2f(piv);
            const float irs = rsqrtf(piv);
            row[j] *= irs;
            w[j] *= irs;
#pragma unroll
            for (int cc = j + 1; cc < 16; ++cc) {
                const float s2 = rdl(row[j], cc);
                row[cc] = fmaf(-row[j], s2, row[cc]);
                w[cc] = fmaf(-s2, w[j], w[cc]);
            }
        }
        if (lane < 16) {
            f16x8 hv0, hv1;
#pragma unroll
            for (int m2 = 0; m2 < 8; ++m2) {
                hv0[m2] = (f16)row[m2];
                hv1[m2] = (f16)row[8 + m2];
            }
            *(f16x8*)(&Lh[lh_base(rbase + lane) + cbase]) = hv0;
            if (lane >= 8) *(f16x8*)(&Lh[lh_base(rbase + lane) + cbase + 8]) = hv1;
        }
        if (lane < 32) {
#pragma unroll
            for (int i = 0; i < 16; ++i)
                mdst[i * 40 + lane] = (lane < 16) ? (f16)w[i] : (f16)0.0f;
        }
    };
    auto stX = [&](const f32x4& x, int rr0, int cb) {
#pragma unroll
        for (int q = 0; q < 4; ++q) {
            const int gr = rr0 + crow + q;
            const f16 h = (f16)x[q];
            if (MODE == 1 && gr >= SPLIT) Gl[(gr - SPLIT) * GSTR + cb + ccol] = h;
            else Lh[lh_base(gr) + cb + ccol] = h;
        }
    };

    for (int jb = 0; jb < ncols; jb += 32) {
        const bool half = (ncols - jb) <= 16;
        const int nkk = jb >> 5;                     // jb always mult of 32
        const int ntile = (rows - jb) >> 4;
        const int nbelow = ntile - (half ? 1 : 2);
        const int rb0 = jb + (half ? 16 : 32);

        // state carried across barrier 1 (per-thread regs)
        bool val_[2] = {false, false};
        int r0_[2] = {0, 0};
        f16x8 afs_[2] = {};
        f32x4 s1_[2] = {};

        if (wv == 0) {
            // ---- wave 0: diag 32-block (t0 rows jb.., t1 rows jb+16..)
            f32x4 g00 = zz, g10 = zz, g11 = zz;
#pragma unroll
            for (int q = 0; q < 4; ++q)
                g00[q] = gath<MODE>(L, S, idx, k, add1, jb + crow + q, jb + ccol);
            if (!half) {
#pragma unroll
                for (int q = 0; q < 4; ++q) {
                    g10[q] = gath<MODE>(L, S, idx, k, add1, jb + 16 + crow + q, jb + ccol);
                    g11[q] = gath<MODE>(L, S, idx, k, add1, jb + 16 + crow + q, jb + 16 + ccol);
                }
            }
            const int bF0 = lh_base(jb + frow) + koff;
            const int bF1 = lh_base(jb + 16 + frow) + koff;
            f32x4 a00 = zz, a10 = zz, a11 = zz;
            for (int c = 0; c < nkk; ++c) {
                const int kk = c << 5;
                const f16x8 F0 = *(const f16x8*)(&Lh[bF0 + kk]);
                a00 = __builtin_amdgcn_mfma_f32_16x16x32_f16(F0, F0, a00, 0, 0, 0);
                if (!half) {
                    const f16x8 F1 = *(const f16x8*)(&Lh[bF1 + kk]);
                    a10 = __builtin_amdgcn_mfma_f32_16x16x32_f16(F1, F0, a10, 0, 0, 0);
                    a11 = __builtin_amdgcn_mfma_f32_16x16x32_f16(F1, F1, a11, 0, 0, 0);
                }
            }
            f32x4 s00;
#pragma unroll
            for (int q = 0; q < 4; ++q) s00[q] = g00[q] - a00[q];
            scr_st(s00);
            factor16(jb, jb, Mm);                    // diag0 + M0
            if (!half) {
                f32x4 s10;
#pragma unroll
                for (int q = 0; q < 4; ++q) s10[q] = g10[q] - a10[q];
                scr_st(s10);
                const f16x8 af10 = ld_af();
                const f16x8 bM0 = *(const f16x8*)(&Mm[frow * 40 + koff]);
                const f32x4 x10 = __builtin_amdgcn_mfma_f32_16x16x32_f16(af10, bM0, zz, 0, 0, 0);
#pragma unroll
                for (int q = 0; q < 4; ++q)          // publish X10 (always Lh rows)
                    Lh[lh_base(jb + 16 + crow + q) + jb + ccol] = (f16)x10[q];
                scr_st(x10);
                const f16x8 afx = ld_af();           // A-frag == B-frag layout
                const f32x4 pr = __builtin_amdgcn_mfma_f32_16x16x32_f16(afx, afx, zz, 0, 0, 0);
                f32x4 s11;
#pragma unroll
                for (int q = 0; q < 4; ++q) s11[q] = g11[q] - a11[q] - pr[q];
                scr_st(s11);
                factor16(jb + 16, jb + 16, Mm + 640);  // diag1 + M1
            }
        } else {
            // ---- waves 1..15: (a) for owned below-tiles, both column blocks
            bool isg_[2];
            int baseA_[2];
#pragma unroll
            for (int it = 0; it < 2; ++it) {
                const int tb = (wv - 1) + 15 * it;
                val_[it] = tb < nbelow;
                const int rr = rb0 + 16 * (val_[it] ? tb : 0);
                r0_[it] = rr;
                isg_[it] = (MODE == 1) && val_[it] && (rr >= SPLIT);
                baseA_[it] = isg_[it] ? ((rr - SPLIT + frow) * GSTR + koff)
                                      : (lh_base(rr + frow) + koff);
            }
            f32x4 g0_[2] = {zz, zz}, g1_[2] = {zz, zz};
#pragma unroll
            for (int it = 0; it < 2; ++it)
                if (val_[it]) {
#pragma unroll
                    for (int q = 0; q < 4; ++q) {
                        g0_[it][q] = gath<MODE>(L, S, idx, k, add1, r0_[it] + crow + q, jb + ccol);
                        if (!half)
                            g1_[it][q] = gath<MODE>(L, S, idx, k, add1, r0_[it] + crow + q, jb + 16 + ccol);
                    }
                }
            const int bB0 = lh_base(jb + frow) + koff;
            const int bB1 = lh_base(jb + 16 + frow) + koff;
            f32x4 ac0_[2] = {zz, zz}, ac1_[2] = {zz, zz};
            for (int c = 0; c < nkk; ++c) {
                const int kk = c << 5;
                const f16x8 B0 = *(const f16x8*)(&Lh[bB0 + kk]);
                f16x8 B1 = {};
                if (!half) B1 = *(const f16x8*)(&Lh[bB1 + kk]);
#pragma unroll
                for (int it = 0; it < 2; ++it)
                    if (val_[it]) {
                        const f16x8 A = isg_[it] ? *(const f16x8*)(&Gl[baseA_[it] + kk])
                                                 : *(const f16x8*)(&Lh[baseA_[it] + kk]);
                        ac0_[it] = __builtin_amdgcn_mfma_f32_16x16x32_f16(A, B0, ac0_[it], 0, 0, 0);
                        if (!half)
                            ac1_[it] = __builtin_amdgcn_mfma_f32_16x16x32_f16(A, B1, ac1_[it], 0, 0, 0);
                    }
            }
            // pre-barrier staging: S0 -> scr -> A-frag regs; S1 stays in C-frags
#pragma unroll
            for (int it = 0; it < 2; ++it)
                if (val_[it]) {
                    f32x4 s0;
#pragma unroll
                    for (int q = 0; q < 4; ++q) s0[q] = g0_[it][q] - ac0_[it][q];
                    scr_st(s0);
                    afs_[it] = ld_af();
                    if (!half) {
#pragma unroll
                        for (int q = 0; q < 4; ++q) s1_[it][q] = g1_[it][q] - ac1_[it][q];
                    }
                }
        }
        __syncthreads();   // barrier 1: M0/M1, diag factor rows, X10 published

        // ---- (c): all below-tile waves (val_ false on wave 0)
        {
            const f16x8 bM0 = *(const f16x8*)(&Mm[frow * 40 + koff]);
            f16x8 bM1 = {}, bX10 = {};
            if (!half) {
                bM1 = *(const f16x8*)(&Mm[640 + frow * 40 + koff]);
                bX10 = *(const f16x8*)(&Lh[lh_base(jb + 16 + frow) + jb + koff]);
            }
#pragma unroll
            for (int it = 0; it < 2; ++it)
                if (val_[it]) {
                    const f32x4 x0 = __builtin_amdgcn_mfma_f32_16x16x32_f16(afs_[it], bM0, zz, 0, 0, 0);
                    stX(x0, r0_[it], jb);
                    if (!half) {
                        scr_st(x0);
                        const f16x8 afx = ld_af();   // zeroed k>=16 (bX10 k>=16 holds diag1!)
                        const f32x4 pr = __builtin_amdgcn_mfma_f32_16x16x32_f16(afx, bX10, zz, 0, 0, 0);
                        f32x4 s1p;
#pragma unroll
                        for (int q = 0; q < 4; ++q) s1p[q] = s1_[it][q] - pr[q];
                        scr_st(s1p);
                        const f16x8 af1 = ld_af();
                        const f32x4 x1 = __builtin_amdgcn_mfma_f32_16x16x32_f16(af1, bM1, zz, 0, 0, 0);
                        stX(x1, r0_[it], jb + 16);
                    }
                }
        }
        __syncthreads();   // barrier 2: factor cols jb..jb+31 published
    }
    return lg2;
}

// ---------- S = A22 - G·G^T, G in LDS; S (fp32) streamed to global ----------
__device__ void schur32(char* arena, float* __restrict__ S,
                        const float* __restrict__ L, const short* idx,
                        int k, int k2p, bool add1) {
    const int tid = threadIdx.x;
    const int lane = tid & 63, wv = tid >> 6;
    const f16* Gl = (const f16*)(arena + G1_OFF);
    const int frow = lane & 15, koff = (lane >> 4) * 8;
    const int crow = (lane >> 4) * 4, ccol = lane & 15;
    const int nt2 = k2p >> 4, TT = (nt2 * (nt2 + 1)) >> 1;
    for (int e = wv; e < TT; e += NW) {
        int R, C;
        tri_map(e, &R, &C);
        const int r0 = R << 4, c0 = C << 4;
        f32x4 g;
#pragma unroll
        for (int q = 0; q < 4; ++q) {
            const int gr = SPLIT + r0 + crow + q, gc = SPLIT + c0 + ccol;
            float v;
            if (gr < k && gc < k) {
                v = L[(int)idx[gr] * N + (int)idx[gc]];
                if (add1 && gr == gc) v += 1.0f;
            } else v = (gr == gc) ? 1.0f : 0.0f;
            g[q] = v;
        }
        const int ba = (r0 + frow) * GSTR + koff, bb = (c0 + frow) * GSTR + koff;
        f32x4 acc = {0.f, 0.f, 0.f, 0.f};
#pragma unroll
        for (int c = 0; c < SPLIT / 32; ++c) {       // 5 aligned chunks
            const f16x8 A = *(const f16x8*)(&Gl[ba + (c << 5)]);
            const f16x8 B = *(const f16x8*)(&Gl[bb + (c << 5)]);
            acc = __builtin_amdgcn_mfma_f32_16x16x32_f16(A, B, acc, 0, 0, 0);
        }
#pragma unroll
        for (int q = 0; q < 4; ++q)
            S[(r0 + crow + q) * SLD2 + c0 + ccol] = g[q] - acc[q];
    }
}

// ---------- one block per batch item; block BATCH = logdet(L+I) ----------
__global__ __launch_bounds__(TPB, 4) void chol_all(const int* __restrict__ x,
                                                   const float* __restrict__ L,
                                                   char* __restrict__ slabs, int nslabs,
                                                   float* __restrict__ logs) {
    const int b = blockIdx.x;
    const int tid = threadIdx.x;
    const int lane = tid & 63, wv = tid >> 6;
    __shared__ __align__(16) char arena[ARENA_SZ];
    __shared__ short idx[N];
    __shared__ int wcnt[NW];

    const bool zc = (b == BATCH);
    const bool inx = tid < N;
    const bool act = zc ? inx : (inx && x[(size_t)b * N + tid] != 0);
    const unsigned long long m = __ballot(act);
    if (lane == 0) wcnt[wv] = __popcll(m);
    __syncthreads();
    int off = 0, ktot = 0;
    for (int q = 0; q < NW; ++q) {
        if (q < wv) off += wcnt[q];
        ktot += wcnt[q];
    }
    if (act) idx[off + __popcll(m & ((1ULL << lane) - 1ULL))] = (short)tid;
    __syncthreads();

    const int k = ktot;
    const int kp = (k + 15) & ~15;

    float lg2;
    if (!zc && kp <= KP) {
        lg2 = chol32<0>(arena, nullptr, L, idx, k, kp, kp, false);
    } else {
        const int si = zc ? 0 : (nslabs > 1 ? 1 + (b % (nslabs - 1)) : 0);
        float* S = (float*)(slabs + (size_t)si * SLAB_BYTES);
        const int k2 = k - SPLIT, k2p = kp - SPLIT;
        lg2 = chol32<1>(arena, nullptr, L, idx, k, kp, SPLIT, zc);
        schur32(arena, S, L, idx, k, k2p, zc);
        __syncthreads();   // all G reads done before stage2 overwrites the arena
        lg2 += chol32<2>(arena, S, L, idx, k2, k2p, k2p, false);
    }
    if (tid == 0) logs[b] = lg2 * LN2;
}

__global__ void finalize(const float* __restrict__ logs, float* __restrict__ out) {
    const int i = threadIdx.x;
    out[i] = logs[i] - logs[BATCH];
}

extern "C" void kernel_launch(void* const* d_in, const int* in_sizes, int n_in,
                              void* d_out, int out_size, void* d_ws, size_t ws_size,
                              hipStream_t stream) {
    const int* x = (const int*)d_in[0];
    const float* B = (const float*)d_in[1];
    float* out = (float*)d_out;

    char* ws = (char*)d_ws;
    const size_t L_bytes = (size_t)N * N * 4;  // 1 MB
    float* L = (float*)ws;
    float* logs = (float*)(ws + L_bytes);
    const size_t head = L_bytes + 4096;
    char* slabs = ws + head;
    int nslabs = (ws_size > head) ? (int)((ws_size - head) / SLAB_BYTES) : 1;
    if (nslabs < 1) nslabs = 1;
    if (nslabs > 9) nslabs = 9;

    compute_L<<<dim3(8, 8), 256, 0, stream>>>(B, L);
    chol_all<<<BATCH + 1, TPB, 0, stream>>>(x, L, slabs, nslabs, logs);
    finalize<<<1, BATCH, 0, stream>>>(logs, out);
}